// Round 1
// baseline (2602.751 us; speedup 1.0000x reference)
//
#include <hip/hip_runtime.h>
#include <hip/hip_bf16.h>

#define N_NODES   100000
#define N_EDGES   3200000
#define N_FEAT    500
#define HIDDEN    128
#define N_CLASSES 64
#define K_LAYERS  10

// ---------------- degree histogram ----------------
__global__ void count_deg_k(const int* __restrict__ dst, int* __restrict__ cnt) {
  int e = blockIdx.x * blockDim.x + threadIdx.x;
  if (e < N_EDGES) atomicAdd(&cnt[dst[e]], 1);
}

__global__ void dinv_k(const int* __restrict__ cnt, float* __restrict__ dinv) {
  int i = blockIdx.x * blockDim.x + threadIdx.x;
  if (i < N_NODES) dinv[i] = rsqrtf((float)(cnt[i] + 1));  // +1 self-loop
}

// ---------------- exclusive scan (1 block, 1024 threads) ----------------
__global__ __launch_bounds__(1024) void scan_k(const int* __restrict__ cnt,
                                               int* __restrict__ offs) {
  __shared__ int sums[1024];
  const int CH = (N_NODES + 1023) / 1024;  // 98
  int t = threadIdx.x;
  int base = t * CH;
  int hi = min(base + CH, N_NODES);
  int s = 0;
  for (int i = base; i < hi; ++i) s += cnt[i];
  sums[t] = s;
  __syncthreads();
  for (int d = 1; d < 1024; d <<= 1) {
    int v = (t >= d) ? sums[t - d] : 0;
    __syncthreads();
    sums[t] += v;
    __syncthreads();
  }
  int run = sums[t] - s;  // exclusive prefix
  for (int i = base; i < hi; ++i) { offs[i] = run; run += cnt[i]; }
  if (t == 0) offs[N_NODES] = N_EDGES;
}

// ---------------- CSR fill (src + norm packed) ----------------
__global__ void fill_csr_k(const int* __restrict__ src, const int* __restrict__ dst,
                           const float* __restrict__ dinv, const int* __restrict__ offs,
                           int* __restrict__ cur, int2* __restrict__ csr) {
  int e = blockIdx.x * blockDim.x + threadIdx.x;
  if (e >= N_EDGES) return;
  int d = dst[e], s = src[e];
  int p = offs[d] + atomicAdd(&cur[d], 1);
  float w = dinv[s] * dinv[d];
  csr[p] = make_int2(s, __float_as_int(w));
}

// ---------------- fp32 register-tiled GEMM (+bias, optional relu) ----------------
// C[M x N] = A[M x KTOT] @ B[KTOT x N] + bias ; block tile 128 x N
template<int N, int KC, int KTOT, bool RELU>
__global__ __launch_bounds__(256) void gemm_k(const float* __restrict__ A,
                                              const float* __restrict__ B,
                                              const float* __restrict__ bias,
                                              float* __restrict__ C, int M) {
  constexpr int TC = N / 8;       // col groups (16 or 8)
  constexpr int TR = 256 / TC;    // row groups
  constexpr int RT = 128 / TR;    // rows per thread (8 or 4)
  constexpr int XPAD = 132;       // pad: conflict-free transpose-write, 16B-aligned rows
  __shared__ __align__(16) float xs[KC][XPAD];
  __shared__ __align__(16) float bs[KC][N];

  int tid = threadIdx.x;
  int tc = tid % TC, tr = tid / TC;
  int row0 = blockIdx.x * 128;
  int c0 = tc * 8;
  int r0 = tr * RT;

  float acc[RT][8];
  #pragma unroll
  for (int i = 0; i < RT; ++i)
    #pragma unroll
    for (int j = 0; j < 8; ++j) acc[i][j] = 0.f;

  int lr = tid & 127;       // staging row
  int half = tid >> 7;      // 0/1
  constexpr int KH = KC / 2;

  for (int kc = 0; kc < KTOT; kc += KC) {
    __syncthreads();
    // stage A (transposed): xs[k][row]
    int gr = row0 + lr;
    const float* ap = A + (size_t)gr * KTOT + kc + half * KH;
    #pragma unroll
    for (int i = 0; i < KH; ++i) {
      float v = (gr < M) ? ap[i] : 0.f;
      xs[half * KH + i][lr] = v;
    }
    // stage B: bs[k][c]
    #pragma unroll
    for (int i = 0; i < KC * N / 256; ++i) {
      int idx = tid + i * 256;
      int kk = idx / N, cc = idx % N;
      bs[kk][cc] = B[(size_t)(kc + kk) * N + cc];
    }
    __syncthreads();
    #pragma unroll 2
    for (int k = 0; k < KC; ++k) {
      float av[RT], bv[8];
      #pragma unroll
      for (int i = 0; i < RT; i += 4) {
        float4 t4 = *reinterpret_cast<const float4*>(&xs[k][r0 + i]);
        av[i] = t4.x; av[i + 1] = t4.y; av[i + 2] = t4.z; av[i + 3] = t4.w;
      }
      #pragma unroll
      for (int j = 0; j < 8; j += 4) {
        float4 t4 = *reinterpret_cast<const float4*>(&bs[k][c0 + j]);
        bv[j] = t4.x; bv[j + 1] = t4.y; bv[j + 2] = t4.z; bv[j + 3] = t4.w;
      }
      #pragma unroll
      for (int i = 0; i < RT; ++i)
        #pragma unroll
        for (int j = 0; j < 8; ++j)
          acc[i][j] += av[i] * bv[j];
    }
  }
  #pragma unroll
  for (int i = 0; i < RT; ++i) {
    int row = row0 + r0 + i;
    if (row < M) {
      #pragma unroll
      for (int j = 0; j < 8; ++j) {
        float v = acc[i][j] + bias[c0 + j];
        if (RELU) v = fmaxf(v, 0.f);
        acc[i][j] = v;
      }
      float4* cp = reinterpret_cast<float4*>(C + (size_t)row * N + c0);
      cp[0] = make_float4(acc[i][0], acc[i][1], acc[i][2], acc[i][3]);
      cp[1] = make_float4(acc[i][4], acc[i][5], acc[i][6], acc[i][7]);
    }
  }
}

// ---------------- propagation: one wave per node, lane = channel ----------------
__global__ __launch_bounds__(256) void prop_k(const float* __restrict__ zin,
                                              float* __restrict__ zout,
                                              const float* __restrict__ h0,
                                              const float* __restrict__ dinv,
                                              const int* __restrict__ offs,
                                              const int2* __restrict__ csr) {
  int lane = threadIdx.x & 63;
  int node = (blockIdx.x * 256 + threadIdx.x) >> 6;
  if (node >= N_NODES) return;
  float di = dinv[node];
  float acc = di * di * zin[(size_t)node * 64 + lane];  // self-loop term
  int beg = offs[node], end = offs[node + 1];
  for (int e = beg; e < end; e += 64) {
    int2 v = (e + lane < end) ? csr[e + lane] : make_int2(0, 0);
    int cnt = min(64, end - e);
    for (int j = 0; j < cnt; ++j) {
      int s = __shfl(v.x, j);
      float w = __int_as_float(__shfl(v.y, j));
      acc += w * zin[(size_t)s * 64 + lane];
    }
  }
  zout[(size_t)node * 64 + lane] =
      0.9f * acc + 0.1f * h0[(size_t)node * 64 + lane];
}

// ---------------- softmax over 64 classes, one wave per row ----------------
__global__ __launch_bounds__(256) void softmax_k(const float* __restrict__ z,
                                                 float* __restrict__ out) {
  int lane = threadIdx.x & 63;
  int row = (blockIdx.x * 256 + threadIdx.x) >> 6;
  if (row >= N_NODES) return;
  float v = z[(size_t)row * 64 + lane];
  float m = v;
  #pragma unroll
  for (int o = 32; o > 0; o >>= 1) m = fmaxf(m, __shfl_xor(m, o));
  float ev = __expf(v - m);
  float s = ev;
  #pragma unroll
  for (int o = 32; o > 0; o >>= 1) s += __shfl_xor(s, o);
  out[(size_t)row * 64 + lane] = ev / s;
}

extern "C" void kernel_launch(void* const* d_in, const int* in_sizes, int n_in,
                              void* d_out, int out_size, void* d_ws, size_t ws_size,
                              hipStream_t stream) {
  const float* x  = (const float*)d_in[0];
  const int*   ei = (const int*)d_in[1];
  const float* W1 = (const float*)d_in[2];
  const float* b1 = (const float*)d_in[3];
  const float* W2 = (const float*)d_in[4];
  const float* b2 = (const float*)d_in[5];
  const int* src = ei;
  const int* dst = ei + N_EDGES;

  char* w = (char*)d_ws;
  // H (51.2MB) is dead after gemm2; zA/zB overlay it.
  float* H  = (float*)w;
  float* zA = H;
  float* zB = H + (size_t)N_NODES * 64;
  size_t off = (size_t)N_NODES * 128 * 4;                    // 51.2 MB
  int2*  csr  = (int2*)(w + off); off += (size_t)N_EDGES * 8; // 25.6 MB
  float* dinv = (float*)(w + off); off += 512 * 1024;
  int*   cnt  = (int*)(w + off);   off += 512 * 1024;
  int*   offs = (int*)(w + off);   off += 512 * 1024;
  int*   cur  = (int*)(w + off);   off += 512 * 1024;
  float* h0 = (float*)d_out;  // fully rewritten by softmax at the end

  hipMemsetAsync(cnt, 0, N_NODES * 4, stream);
  hipMemsetAsync(cur, 0, N_NODES * 4, stream);

  count_deg_k<<<(N_EDGES + 255) / 256, 256, 0, stream>>>(dst, cnt);
  dinv_k<<<(N_NODES + 255) / 256, 256, 0, stream>>>(cnt, dinv);
  scan_k<<<1, 1024, 0, stream>>>(cnt, offs);
  fill_csr_k<<<(N_EDGES + 255) / 256, 256, 0, stream>>>(src, dst, dinv, offs, cur, csr);

  gemm_k<128, 50, 500, true><<<(N_NODES + 127) / 128, 256, 0, stream>>>(x, W1, b1, H, N_NODES);
  gemm_k<64, 64, 128, false><<<(N_NODES + 127) / 128, 256, 0, stream>>>(H, W2, b2, h0, N_NODES);

  const float* zi = h0;
  float* zo = zA;
  for (int it = 0; it < K_LAYERS; ++it) {
    prop_k<<<(N_NODES * 64) / 256, 256, 0, stream>>>(zi, zo, h0, dinv, offs, csr);
    zi = zo;
    zo = (zo == zA) ? zB : zA;
  }
  softmax_k<<<(N_NODES * 64) / 256, 256, 0, stream>>>(zi, (float*)d_out);
}

// Round 2
// 1741.005 us; speedup vs baseline: 1.4950x; 1.4950x over previous
//
#include <hip/hip_runtime.h>
#include <hip/hip_bf16.h>

#define N_NODES   100000
#define N_EDGES   3200000
#define N_FEAT    500
#define HIDDEN    128
#define N_CLASSES 64
#define K_LAYERS  10

typedef __attribute__((ext_vector_type(8))) short bf16x8;
typedef __attribute__((ext_vector_type(4))) float f32x4;

__device__ inline ushort f2bf_rn(float f) {
  unsigned u = __float_as_uint(f);
  unsigned r = (u + 0x7FFFu + ((u >> 16) & 1u)) >> 16;
  return (ushort)r;
}
__device__ inline float bf2f(ushort h) {
  return __uint_as_float(((unsigned)h) << 16);
}

// ---------------- degree histogram ----------------
__global__ void count_deg_k(const int* __restrict__ dst, int* __restrict__ cnt) {
  int e = blockIdx.x * blockDim.x + threadIdx.x;
  if (e < N_EDGES) atomicAdd(&cnt[dst[e]], 1);
}

__global__ void dinv_k(const int* __restrict__ cnt, float* __restrict__ dinv) {
  int i = blockIdx.x * blockDim.x + threadIdx.x;
  if (i < N_NODES) dinv[i] = rsqrtf((float)(cnt[i] + 1));  // +1 self-loop
}

// ---------------- exclusive scan (1 block, 1024 threads) ----------------
__global__ __launch_bounds__(1024) void scan_k(const int* __restrict__ cnt,
                                               int* __restrict__ offs) {
  __shared__ int sums[1024];
  const int CH = (N_NODES + 1023) / 1024;  // 98
  int t = threadIdx.x;
  int base = t * CH;
  int hi = min(base + CH, N_NODES);
  int s = 0;
  for (int i = base; i < hi; ++i) s += cnt[i];
  sums[t] = s;
  __syncthreads();
  for (int d = 1; d < 1024; d <<= 1) {
    int v = (t >= d) ? sums[t - d] : 0;
    __syncthreads();
    sums[t] += v;
    __syncthreads();
  }
  int run = sums[t] - s;  // exclusive prefix
  for (int i = base; i < hi; ++i) { offs[i] = run; run += cnt[i]; }
  if (t == 0) offs[N_NODES] = N_EDGES;
}

// ---------------- CSR fill (src + norm packed) ----------------
__global__ void fill_csr_k(const int* __restrict__ src, const int* __restrict__ dst,
                           const float* __restrict__ dinv, const int* __restrict__ offs,
                           int* __restrict__ cur, int2* __restrict__ csr) {
  int e = blockIdx.x * blockDim.x + threadIdx.x;
  if (e >= N_EDGES) return;
  int d = dst[e], s = src[e];
  int p = offs[d] + atomicAdd(&cur[d], 1);
  float w = dinv[s] * dinv[d];
  csr[p] = make_int2(s, __float_as_int(w));
}

// ---------------- W^T bf16 hi/lo prep: W[K][N] -> WT[N][KPAD] ----------------
__global__ void prep_wt_k(const float* __restrict__ W, ushort* __restrict__ hi,
                          ushort* __restrict__ lo, int K, int N, int KPAD) {
  int idx = blockIdx.x * 256 + threadIdx.x;
  if (idx >= N * KPAD) return;
  int n = idx / KPAD, k = idx - n * KPAD;
  float v = (k < K) ? W[(size_t)k * N + n] : 0.f;
  ushort h = f2bf_rn(v);
  ushort l = f2bf_rn(v - bf2f(h));
  hi[idx] = h;
  lo[idx] = l;
}

// ---------------- split-bf16 MFMA GEMM: C[M x BN] = A[M x KTOT] @ B + bias ----
// Block: 256 threads (4 waves as 2x2), tile 128 x BN, K-step 64.
// LDS swizzle: 16B chunk index XOR (row&7) -> conflict-free-ish ds_read_b128.
template<int BN, int KTOT, int KPAD, bool RELU>
__global__ __launch_bounds__(256, 2) void mfma_gemm_k(
    const float* __restrict__ A, const ushort* __restrict__ BThi,
    const ushort* __restrict__ BTlo, const float* __restrict__ bias,
    float* __restrict__ C, int M) {
  constexpr int BK = 64;
  constexpr int NF = BN / 32;  // n-frags per wave
  __shared__ __align__(16) ushort sm[(2 * 128 + 2 * BN) * BK];
  ushort* Ahi = sm;
  ushort* Alo = sm + 128 * BK;
  ushort* Bhi = sm + 2 * 128 * BK;
  ushort* Blo = Bhi + BN * BK;

  int tid = threadIdx.x;
  int lane = tid & 63, wid = tid >> 6;
  int wm = wid >> 1, wn = wid & 1;
  int lrow = lane & 15, lg = lane >> 4;
  int row0 = blockIdx.x * 128;

  f32x4 acc[4][NF];
  #pragma unroll
  for (int m = 0; m < 4; ++m)
    #pragma unroll
    for (int n = 0; n < NF; ++n) acc[m][n] = (f32x4){0.f, 0.f, 0.f, 0.f};

  for (int kc = 0; kc < KPAD; kc += BK) {
    __syncthreads();
    // ---- stage A (fp32 -> bf16 hi/lo), 128 rows x 64 k ----
    #pragma unroll
    for (int i = 0; i < 8; ++i) {
      int c = tid + i * 256;               // 0..2047 (128 rows x 16 float4)
      int r = c >> 4, k4 = (c & 15) << 2;
      int gr = row0 + r, gk = kc + k4;
      float4 v = make_float4(0.f, 0.f, 0.f, 0.f);
      if (gr < M) {
        if (gk + 3 < KTOT) {
          v = *(const float4*)(A + (size_t)gr * KTOT + gk);
        } else {
          float* vp = &v.x;
          #pragma unroll
          for (int e = 0; e < 4; ++e)
            if (gk + e < KTOT) vp[e] = A[(size_t)gr * KTOT + gk + e];
        }
      }
      ushort h0 = f2bf_rn(v.x), h1 = f2bf_rn(v.y), h2 = f2bf_rn(v.z), h3 = f2bf_rn(v.w);
      ushort l0 = f2bf_rn(v.x - bf2f(h0)), l1 = f2bf_rn(v.y - bf2f(h1));
      ushort l2 = f2bf_rn(v.z - bf2f(h2)), l3 = f2bf_rn(v.w - bf2f(h3));
      int chunk = k4 >> 3, sub = k4 & 4;
      int ad = r * 64 + ((chunk << 3) ^ ((r & 7) << 3)) + sub;
      *(ushort4*)(Ahi + ad) = make_ushort4(h0, h1, h2, h3);
      *(ushort4*)(Alo + ad) = make_ushort4(l0, l1, l2, l3);
    }
    // ---- stage B (precomputed bf16 hi/lo, transposed), BN rows x 64 k ----
    #pragma unroll
    for (int i = 0; i < BN * 8 / 256; ++i) {
      int c = tid + i * 256;               // chunk id over BN*8
      int n = c >> 3, ch = c & 7;
      int gk = kc + ch * 8;
      int ad = n * 64 + ((ch << 3) ^ ((n & 7) << 3));
      *(uint4*)(Bhi + ad) = *(const uint4*)(BThi + (size_t)n * KPAD + gk);
      *(uint4*)(Blo + ad) = *(const uint4*)(BTlo + (size_t)n * KPAD + gk);
    }
    __syncthreads();
    // ---- MFMA: 2 k-subs of 32 ----
    #pragma unroll
    for (int ks = 0; ks < 2; ++ks) {
      bf16x8 ah[4], al[4], bh[NF], bl[NF];
      #pragma unroll
      for (int m = 0; m < 4; ++m) {
        int r = wm * 64 + m * 16 + lrow;
        int ad = r * 64 + (((ks * 4 + lg) << 3) ^ ((r & 7) << 3));
        ah[m] = *(const bf16x8*)(Ahi + ad);
        al[m] = *(const bf16x8*)(Alo + ad);
      }
      #pragma unroll
      for (int n = 0; n < NF; ++n) {
        int r = wn * (BN / 2) + n * 16 + lrow;
        int ad = r * 64 + (((ks * 4 + lg) << 3) ^ ((r & 7) << 3));
        bh[n] = *(const bf16x8*)(Bhi + ad);
        bl[n] = *(const bf16x8*)(Blo + ad);
      }
      #pragma unroll
      for (int m = 0; m < 4; ++m)
        #pragma unroll
        for (int n = 0; n < NF; ++n) {
          acc[m][n] = __builtin_amdgcn_mfma_f32_16x16x32_bf16(ah[m], bh[n], acc[m][n], 0, 0, 0);
          acc[m][n] = __builtin_amdgcn_mfma_f32_16x16x32_bf16(ah[m], bl[n], acc[m][n], 0, 0, 0);
          acc[m][n] = __builtin_amdgcn_mfma_f32_16x16x32_bf16(al[m], bh[n], acc[m][n], 0, 0, 0);
        }
    }
  }
  // ---- epilogue: C/D layout col=lane&15, row=(lane>>4)*4+reg (verified) ----
  #pragma unroll
  for (int m = 0; m < 4; ++m)
    #pragma unroll
    for (int n = 0; n < NF; ++n) {
      int gcol = wn * (BN / 2) + n * 16 + lrow;
      float bb = bias[gcol];
      #pragma unroll
      for (int r = 0; r < 4; ++r) {
        int grow = row0 + wm * 64 + m * 16 + lg * 4 + r;
        if (grow < M) {
          float v = acc[m][n][r] + bb;
          if (RELU) v = fmaxf(v, 0.f);
          C[(size_t)grow * BN + gcol] = v;
        }
      }
    }
}

// ---------------- propagation: one wave per node, lane = channel ----------------
// Edge records staged wave-locally in LDS (broadcast reads), inner loop
// unrolled x4 for memory-level parallelism (pad entries have w=0, s=0).
__global__ __launch_bounds__(256) void prop_k(const float* __restrict__ zin,
                                              float* __restrict__ zout,
                                              const float* __restrict__ h0,
                                              const float* __restrict__ dinv,
                                              const int* __restrict__ offs,
                                              const int2* __restrict__ csr) {
  __shared__ int2 ebuf[4][64];
  int lane = threadIdx.x & 63;
  int wid = threadIdx.x >> 6;
  int node = (blockIdx.x << 2) + wid;
  if (node >= N_NODES) return;
  float di = dinv[node];
  size_t nb = (size_t)node * 64 + lane;
  float acc = di * di * zin[nb];  // self-loop term
  int beg = offs[node], end = offs[node + 1];
  for (int e = beg; e < end; e += 64) {
    int2 v = (e + lane < end) ? csr[e + lane] : make_int2(0, 0);
    ebuf[wid][lane] = v;
    int cnt = min(64, end - e);
    for (int j = 0; j < cnt; j += 4) {
      int2 v0 = ebuf[wid][j + 0];
      int2 v1 = ebuf[wid][j + 1];
      int2 v2 = ebuf[wid][j + 2];
      int2 v3 = ebuf[wid][j + 3];
      float z0 = zin[(size_t)v0.x * 64 + lane];
      float z1 = zin[(size_t)v1.x * 64 + lane];
      float z2 = zin[(size_t)v2.x * 64 + lane];
      float z3 = zin[(size_t)v3.x * 64 + lane];
      acc += __int_as_float(v0.y) * z0;
      acc += __int_as_float(v1.y) * z1;
      acc += __int_as_float(v2.y) * z2;
      acc += __int_as_float(v3.y) * z3;
    }
  }
  zout[nb] = 0.9f * acc + 0.1f * h0[nb];
}

// ---------------- softmax over 64 classes, one wave per row ----------------
__global__ __launch_bounds__(256) void softmax_k(const float* __restrict__ z,
                                                 float* __restrict__ out) {
  int lane = threadIdx.x & 63;
  int row = (blockIdx.x * 256 + threadIdx.x) >> 6;
  if (row >= N_NODES) return;
  float v = z[(size_t)row * 64 + lane];
  float m = v;
  #pragma unroll
  for (int o = 32; o > 0; o >>= 1) m = fmaxf(m, __shfl_xor(m, o));
  float ev = __expf(v - m);
  float s = ev;
  #pragma unroll
  for (int o = 32; o > 0; o >>= 1) s += __shfl_xor(s, o);
  out[(size_t)row * 64 + lane] = ev / s;
}

extern "C" void kernel_launch(void* const* d_in, const int* in_sizes, int n_in,
                              void* d_out, int out_size, void* d_ws, size_t ws_size,
                              hipStream_t stream) {
  const float* x  = (const float*)d_in[0];
  const int*   ei = (const int*)d_in[1];
  const float* W1 = (const float*)d_in[2];
  const float* b1 = (const float*)d_in[3];
  const float* W2 = (const float*)d_in[4];
  const float* b2 = (const float*)d_in[5];
  const int* src = ei;
  const int* dst = ei + N_EDGES;

  char* w = (char*)d_ws;
  // H (51.2MB) is dead after gemm2; zA/zB overlay it.
  float* H  = (float*)w;
  float* zA = H;
  float* zB = H + (size_t)N_NODES * 64;
  size_t off = (size_t)N_NODES * 128 * 4;                     // 51.2 MB
  int2*   csr   = (int2*)(w + off);   off += (size_t)N_EDGES * 8;  // 25.6 MB
  float*  dinv  = (float*)(w + off);  off += 512 * 1024;
  int*    cnt   = (int*)(w + off);    off += 512 * 1024;
  int*    offs  = (int*)(w + off);    off += 512 * 1024;
  int*    cur   = (int*)(w + off);    off += 512 * 1024;
  ushort* w1thi = (ushort*)(w + off); off += 128 * 512 * 2;
  ushort* w1tlo = (ushort*)(w + off); off += 128 * 512 * 2;
  ushort* w2thi = (ushort*)(w + off); off += 64 * 128 * 2;
  ushort* w2tlo = (ushort*)(w + off); off += 64 * 128 * 2;
  float* h0 = (float*)d_out;  // fully rewritten by softmax at the end

  hipMemsetAsync(cnt, 0, N_NODES * 4, stream);
  hipMemsetAsync(cur, 0, N_NODES * 4, stream);

  count_deg_k<<<(N_EDGES + 255) / 256, 256, 0, stream>>>(dst, cnt);
  dinv_k<<<(N_NODES + 255) / 256, 256, 0, stream>>>(cnt, dinv);
  scan_k<<<1, 1024, 0, stream>>>(cnt, offs);
  fill_csr_k<<<(N_EDGES + 255) / 256, 256, 0, stream>>>(src, dst, dinv, offs, cur, csr);

  prep_wt_k<<<(128 * 512 + 255) / 256, 256, 0, stream>>>(W1, w1thi, w1tlo, 500, 128, 512);
  prep_wt_k<<<(64 * 128 + 255) / 256, 256, 0, stream>>>(W2, w2thi, w2tlo, 128, 64, 128);

  mfma_gemm_k<128, 500, 512, true><<<(N_NODES + 127) / 128, 256, 0, stream>>>(
      x, w1thi, w1tlo, b1, H, N_NODES);
  mfma_gemm_k<64, 128, 128, false><<<(N_NODES + 127) / 128, 256, 0, stream>>>(
      H, w2thi, w2tlo, b2, h0, N_NODES);

  const float* zi = h0;
  float* zo = zA;
  for (int it = 0; it < K_LAYERS; ++it) {
    prop_k<<<(N_NODES + 3) / 4, 256, 0, stream>>>(zi, zo, h0, dinv, offs, csr);
    zi = zo;
    zo = (zo == zA) ? zB : zA;
  }
  softmax_k<<<(N_NODES * 64) / 256, 256, 0, stream>>>(zi, (float*)d_out);
}

// Round 3
// 1728.707 us; speedup vs baseline: 1.5056x; 1.0071x over previous
//
#include <hip/hip_runtime.h>
#include <hip/hip_bf16.h>

#define N_NODES   100000
#define N_EDGES   3200000
#define N_FEAT    500
#define HIDDEN    128
#define N_CLASSES 64
#define K_LAYERS  10

typedef __attribute__((ext_vector_type(8))) short bf16x8;
typedef __attribute__((ext_vector_type(4))) float f32x4;

__device__ inline ushort f2bf_rn(float f) {
  unsigned u = __float_as_uint(f);
  unsigned r = (u + 0x7FFFu + ((u >> 16) & 1u)) >> 16;
  return (ushort)r;
}
__device__ inline float bf2f(ushort h) {
  return __uint_as_float(((unsigned)h) << 16);
}

// ---------------- degree histogram ----------------
__global__ void count_deg_k(const int* __restrict__ dst, int* __restrict__ cnt) {
  int e = blockIdx.x * blockDim.x + threadIdx.x;
  if (e < N_EDGES) atomicAdd(&cnt[dst[e]], 1);
}

__global__ void dinv_k(const int* __restrict__ cnt, float* __restrict__ dinv) {
  int i = blockIdx.x * blockDim.x + threadIdx.x;
  if (i < N_NODES) dinv[i] = rsqrtf((float)(cnt[i] + 1));  // +1 self-loop
}

// ---------------- exclusive scan (1 block, 1024 threads) ----------------
__global__ __launch_bounds__(1024) void scan_k(const int* __restrict__ cnt,
                                               int* __restrict__ offs) {
  __shared__ int sums[1024];
  const int CH = (N_NODES + 1023) / 1024;  // 98
  int t = threadIdx.x;
  int base = t * CH;
  int hi = min(base + CH, N_NODES);
  int s = 0;
  for (int i = base; i < hi; ++i) s += cnt[i];
  sums[t] = s;
  __syncthreads();
  for (int d = 1; d < 1024; d <<= 1) {
    int v = (t >= d) ? sums[t - d] : 0;
    __syncthreads();
    sums[t] += v;
    __syncthreads();
  }
  int run = sums[t] - s;  // exclusive prefix
  for (int i = base; i < hi; ++i) { offs[i] = run; run += cnt[i]; }
  if (t == 0) offs[N_NODES] = N_EDGES;
}

// ---------------- CSR fill (src + norm packed) ----------------
__global__ void fill_csr_k(const int* __restrict__ src, const int* __restrict__ dst,
                           const float* __restrict__ dinv, const int* __restrict__ offs,
                           int* __restrict__ cur, int2* __restrict__ csr) {
  int e = blockIdx.x * blockDim.x + threadIdx.x;
  if (e >= N_EDGES) return;
  int d = dst[e], s = src[e];
  int p = offs[d] + atomicAdd(&cur[d], 1);
  float w = dinv[s] * dinv[d];
  csr[p] = make_int2(s, __float_as_int(w));
}

// ---------------- W^T bf16 hi/lo prep: W[K][N] -> WT[N][KPAD] ----------------
__global__ void prep_wt_k(const float* __restrict__ W, ushort* __restrict__ hi,
                          ushort* __restrict__ lo, int K, int N, int KPAD) {
  int idx = blockIdx.x * 256 + threadIdx.x;
  if (idx >= N * KPAD) return;
  int n = idx / KPAD, k = idx - n * KPAD;
  float v = (k < K) ? W[(size_t)k * N + n] : 0.f;
  ushort h = f2bf_rn(v);
  ushort l = f2bf_rn(v - bf2f(h));
  hi[idx] = h;
  lo[idx] = l;
}

// ---------------- split-bf16 MFMA GEMM: C[M x BN] = A[M x KTOT] @ B + bias ----
// Block: 256 threads (4 waves as 2x2), tile 128 x BN, K-step 64.
// LDS swizzle: 16B chunk index XOR (row&7) -> conflict-free-ish ds_read_b128.
template<int BN, int KTOT, int KPAD, bool RELU>
__global__ __launch_bounds__(256, 2) void mfma_gemm_k(
    const float* __restrict__ A, const ushort* __restrict__ BThi,
    const ushort* __restrict__ BTlo, const float* __restrict__ bias,
    float* __restrict__ C, int M) {
  constexpr int BK = 64;
  constexpr int NF = BN / 32;  // n-frags per wave
  __shared__ __align__(16) ushort sm[(2 * 128 + 2 * BN) * BK];
  ushort* Ahi = sm;
  ushort* Alo = sm + 128 * BK;
  ushort* Bhi = sm + 2 * 128 * BK;
  ushort* Blo = Bhi + BN * BK;

  int tid = threadIdx.x;
  int lane = tid & 63, wid = tid >> 6;
  int wm = wid >> 1, wn = wid & 1;
  int lrow = lane & 15, lg = lane >> 4;
  int row0 = blockIdx.x * 128;

  f32x4 acc[4][NF];
  #pragma unroll
  for (int m = 0; m < 4; ++m)
    #pragma unroll
    for (int n = 0; n < NF; ++n) acc[m][n] = (f32x4){0.f, 0.f, 0.f, 0.f};

  for (int kc = 0; kc < KPAD; kc += BK) {
    __syncthreads();
    // ---- stage A (fp32 -> bf16 hi/lo), 128 rows x 64 k ----
    #pragma unroll
    for (int i = 0; i < 8; ++i) {
      int c = tid + i * 256;               // 0..2047 (128 rows x 16 float4)
      int r = c >> 4, k4 = (c & 15) << 2;
      int gr = row0 + r, gk = kc + k4;
      float4 v = make_float4(0.f, 0.f, 0.f, 0.f);
      if (gr < M) {
        if (gk + 3 < KTOT) {
          v = *(const float4*)(A + (size_t)gr * KTOT + gk);
        } else {
          float* vp = &v.x;
          #pragma unroll
          for (int e = 0; e < 4; ++e)
            if (gk + e < KTOT) vp[e] = A[(size_t)gr * KTOT + gk + e];
        }
      }
      ushort h0 = f2bf_rn(v.x), h1 = f2bf_rn(v.y), h2 = f2bf_rn(v.z), h3 = f2bf_rn(v.w);
      ushort l0 = f2bf_rn(v.x - bf2f(h0)), l1 = f2bf_rn(v.y - bf2f(h1));
      ushort l2 = f2bf_rn(v.z - bf2f(h2)), l3 = f2bf_rn(v.w - bf2f(h3));
      int chunk = k4 >> 3, sub = k4 & 4;
      int ad = r * 64 + ((chunk << 3) ^ ((r & 7) << 3)) + sub;
      *(ushort4*)(Ahi + ad) = make_ushort4(h0, h1, h2, h3);
      *(ushort4*)(Alo + ad) = make_ushort4(l0, l1, l2, l3);
    }
    // ---- stage B (precomputed bf16 hi/lo, transposed), BN rows x 64 k ----
    #pragma unroll
    for (int i = 0; i < BN * 8 / 256; ++i) {
      int c = tid + i * 256;               // chunk id over BN*8
      int n = c >> 3, ch = c & 7;
      int gk = kc + ch * 8;
      int ad = n * 64 + ((ch << 3) ^ ((n & 7) << 3));
      *(uint4*)(Bhi + ad) = *(const uint4*)(BThi + (size_t)n * KPAD + gk);
      *(uint4*)(Blo + ad) = *(const uint4*)(BTlo + (size_t)n * KPAD + gk);
    }
    __syncthreads();
    // ---- MFMA: 2 k-subs of 32 ----
    #pragma unroll
    for (int ks = 0; ks < 2; ++ks) {
      bf16x8 ah[4], al[4], bh[NF], bl[NF];
      #pragma unroll
      for (int m = 0; m < 4; ++m) {
        int r = wm * 64 + m * 16 + lrow;
        int ad = r * 64 + (((ks * 4 + lg) << 3) ^ ((r & 7) << 3));
        ah[m] = *(const bf16x8*)(Ahi + ad);
        al[m] = *(const bf16x8*)(Alo + ad);
      }
      #pragma unroll
      for (int n = 0; n < NF; ++n) {
        int r = wn * (BN / 2) + n * 16 + lrow;
        int ad = r * 64 + (((ks * 4 + lg) << 3) ^ ((r & 7) << 3));
        bh[n] = *(const bf16x8*)(Bhi + ad);
        bl[n] = *(const bf16x8*)(Blo + ad);
      }
      #pragma unroll
      for (int m = 0; m < 4; ++m)
        #pragma unroll
        for (int n = 0; n < NF; ++n) {
          acc[m][n] = __builtin_amdgcn_mfma_f32_16x16x32_bf16(ah[m], bh[n], acc[m][n], 0, 0, 0);
          acc[m][n] = __builtin_amdgcn_mfma_f32_16x16x32_bf16(ah[m], bl[n], acc[m][n], 0, 0, 0);
          acc[m][n] = __builtin_amdgcn_mfma_f32_16x16x32_bf16(al[m], bh[n], acc[m][n], 0, 0, 0);
        }
    }
  }
  // ---- epilogue: C/D layout col=lane&15, row=(lane>>4)*4+reg (verified) ----
  #pragma unroll
  for (int m = 0; m < 4; ++m)
    #pragma unroll
    for (int n = 0; n < NF; ++n) {
      int gcol = wn * (BN / 2) + n * 16 + lrow;
      float bb = bias[gcol];
      #pragma unroll
      for (int r = 0; r < 4; ++r) {
        int grow = row0 + wm * 64 + m * 16 + lg * 4 + r;
        if (grow < M) {
          float v = acc[m][n][r] + bb;
          if (RELU) v = fmaxf(v, 0.f);
          C[(size_t)grow * BN + gcol] = v;
        }
      }
    }
}

// ---------------- propagation v2: one wave per node ----------------
// lane = 4 channels (float4), 16 lanes per edge -> 4 edges per wave-load (1KB),
// inner loop keeps 4 dwordx4 loads (16 edges) in flight. Each 16-lane group
// accumulates a partial over all 64 channels; xor-reduce (16,32) merges groups.
// Pad edges resolve to z[0] with w=0 (L1-hot, harmless).
__global__ __launch_bounds__(256) void prop_k(const float* __restrict__ zin,
                                              float* __restrict__ zout,
                                              const float* __restrict__ h0,
                                              const float* __restrict__ dinv,
                                              const int* __restrict__ offs,
                                              const int2* __restrict__ csr) {
  int lane = threadIdx.x & 63;
  int wid = threadIdx.x >> 6;
  int node = (blockIdx.x << 2) + wid;
  if (node >= N_NODES) return;
  int grp = lane >> 4;   // which edge within a group of 4
  int lc = lane & 15;    // float4 slot within the 64-channel row
  const float4* zin4 = (const float4*)zin;

  float4 acc = make_float4(0.f, 0.f, 0.f, 0.f);
  int beg = offs[node], end = offs[node + 1];
  for (int e = beg; e < end; e += 64) {
    int2 v = (e + lane < end) ? csr[e + lane] : make_int2(0, 0);
    int cnt = min(64, end - e);
    for (int j = 0; j < cnt; j += 16) {
      int s0 = __shfl(v.x, j + grp);
      int s1 = __shfl(v.x, j + 4 + grp);
      int s2 = __shfl(v.x, j + 8 + grp);
      int s3 = __shfl(v.x, j + 12 + grp);
      float w0 = __int_as_float(__shfl(v.y, j + grp));
      float w1 = __int_as_float(__shfl(v.y, j + 4 + grp));
      float w2 = __int_as_float(__shfl(v.y, j + 8 + grp));
      float w3 = __int_as_float(__shfl(v.y, j + 12 + grp));
      float4 z0 = zin4[(size_t)s0 * 16 + lc];
      float4 z1 = zin4[(size_t)s1 * 16 + lc];
      float4 z2 = zin4[(size_t)s2 * 16 + lc];
      float4 z3 = zin4[(size_t)s3 * 16 + lc];
      acc.x += w0 * z0.x; acc.y += w0 * z0.y; acc.z += w0 * z0.z; acc.w += w0 * z0.w;
      acc.x += w1 * z1.x; acc.y += w1 * z1.y; acc.z += w1 * z1.z; acc.w += w1 * z1.w;
      acc.x += w2 * z2.x; acc.y += w2 * z2.y; acc.z += w2 * z2.z; acc.w += w2 * z2.w;
      acc.x += w3 * z3.x; acc.y += w3 * z3.y; acc.z += w3 * z3.z; acc.w += w3 * z3.w;
    }
  }
  // merge the 4 group-partials (lanes differing in bits 4,5)
  #pragma unroll
  for (int off = 16; off <= 32; off <<= 1) {
    acc.x += __shfl_xor(acc.x, off);
    acc.y += __shfl_xor(acc.y, off);
    acc.z += __shfl_xor(acc.z, off);
    acc.w += __shfl_xor(acc.w, off);
  }
  if (grp == 0) {
    float di = dinv[node];
    float sw = di * di;
    float4 zs = zin4[(size_t)node * 16 + lc];
    float4 h4 = ((const float4*)h0)[(size_t)node * 16 + lc];
    float4 r;
    r.x = 0.9f * (acc.x + sw * zs.x) + 0.1f * h4.x;
    r.y = 0.9f * (acc.y + sw * zs.y) + 0.1f * h4.y;
    r.z = 0.9f * (acc.z + sw * zs.z) + 0.1f * h4.z;
    r.w = 0.9f * (acc.w + sw * zs.w) + 0.1f * h4.w;
    ((float4*)zout)[(size_t)node * 16 + lc] = r;
  }
}

// ---------------- softmax over 64 classes, one wave per row ----------------
__global__ __launch_bounds__(256) void softmax_k(const float* __restrict__ z,
                                                 float* __restrict__ out) {
  int lane = threadIdx.x & 63;
  int row = (blockIdx.x * 256 + threadIdx.x) >> 6;
  if (row >= N_NODES) return;
  float v = z[(size_t)row * 64 + lane];
  float m = v;
  #pragma unroll
  for (int o = 32; o > 0; o >>= 1) m = fmaxf(m, __shfl_xor(m, o));
  float ev = __expf(v - m);
  float s = ev;
  #pragma unroll
  for (int o = 32; o > 0; o >>= 1) s += __shfl_xor(s, o);
  out[(size_t)row * 64 + lane] = ev / s;
}

extern "C" void kernel_launch(void* const* d_in, const int* in_sizes, int n_in,
                              void* d_out, int out_size, void* d_ws, size_t ws_size,
                              hipStream_t stream) {
  const float* x  = (const float*)d_in[0];
  const int*   ei = (const int*)d_in[1];
  const float* W1 = (const float*)d_in[2];
  const float* b1 = (const float*)d_in[3];
  const float* W2 = (const float*)d_in[4];
  const float* b2 = (const float*)d_in[5];
  const int* src = ei;
  const int* dst = ei + N_EDGES;

  char* w = (char*)d_ws;
  // H (51.2MB) is dead after gemm2; zA/zB overlay it.
  float* H  = (float*)w;
  float* zA = H;
  float* zB = H + (size_t)N_NODES * 64;
  size_t off = (size_t)N_NODES * 128 * 4;                     // 51.2 MB
  int2*   csr   = (int2*)(w + off);   off += (size_t)N_EDGES * 8;  // 25.6 MB
  float*  dinv  = (float*)(w + off);  off += 512 * 1024;
  int*    cnt   = (int*)(w + off);    off += 512 * 1024;
  int*    offs  = (int*)(w + off);    off += 512 * 1024;
  int*    cur   = (int*)(w + off);    off += 512 * 1024;
  ushort* w1thi = (ushort*)(w + off); off += 128 * 512 * 2;
  ushort* w1tlo = (ushort*)(w + off); off += 128 * 512 * 2;
  ushort* w2thi = (ushort*)(w + off); off += 64 * 128 * 2;
  ushort* w2tlo = (ushort*)(w + off); off += 64 * 128 * 2;
  float* h0 = (float*)d_out;  // fully rewritten by softmax at the end

  hipMemsetAsync(cnt, 0, N_NODES * 4, stream);
  hipMemsetAsync(cur, 0, N_NODES * 4, stream);

  count_deg_k<<<(N_EDGES + 255) / 256, 256, 0, stream>>>(dst, cnt);
  dinv_k<<<(N_NODES + 255) / 256, 256, 0, stream>>>(cnt, dinv);
  scan_k<<<1, 1024, 0, stream>>>(cnt, offs);
  fill_csr_k<<<(N_EDGES + 255) / 256, 256, 0, stream>>>(src, dst, dinv, offs, cur, csr);

  prep_wt_k<<<(128 * 512 + 255) / 256, 256, 0, stream>>>(W1, w1thi, w1tlo, 500, 128, 512);
  prep_wt_k<<<(64 * 128 + 255) / 256, 256, 0, stream>>>(W2, w2thi, w2tlo, 128, 64, 128);

  mfma_gemm_k<128, 500, 512, true><<<(N_NODES + 127) / 128, 256, 0, stream>>>(
      x, w1thi, w1tlo, b1, H, N_NODES);
  mfma_gemm_k<64, 128, 128, false><<<(N_NODES + 127) / 128, 256, 0, stream>>>(
      H, w2thi, w2tlo, b2, h0, N_NODES);

  const float* zi = h0;
  float* zo = zA;
  for (int it = 0; it < K_LAYERS; ++it) {
    prop_k<<<(N_NODES + 3) / 4, 256, 0, stream>>>(zi, zo, h0, dinv, offs, csr);
    zi = zo;
    zo = (zo == zA) ? zB : zA;
  }
  softmax_k<<<(N_NODES * 64) / 256, 256, 0, stream>>>(zi, (float*)d_out);
}